// Round 1
// baseline (381.180 us; speedup 1.0000x reference)
//
#include <hip/hip_runtime.h>
#include <hip/hip_bf16.h>

#define NN 1024
#define IN_CH 128
#define EDGE_CH 32
#define OUT_CH 128

typedef __attribute__((ext_vector_type(8))) short bf16x8;
typedef __attribute__((ext_vector_type(4))) float f32x4;

// round-to-nearest-even float -> bf16 (bit trick; no NaN inputs here)
static __device__ __forceinline__ short f2bf(float f) {
    union { float f; unsigned u; } v; v.f = f;
    unsigned r = v.u + 0x7FFFu + ((v.u >> 16) & 1u);
    return (short)(r >> 16);
}

// Kernel A: P = node_mat @ node_weight, R = node_mat @ root   [1024 x 128] each
// grid 256 blocks x 128 threads; each block does 4 rows.
__global__ void node_gemm_kernel(const float* __restrict__ node_mat,
                                 const float* __restrict__ node_weight,
                                 const float* __restrict__ root,
                                 float* __restrict__ P, float* __restrict__ R) {
    __shared__ float nm[4 * IN_CH];
    int tid = threadIdx.x;
    int i0 = blockIdx.x * 4;
    for (int idx = tid; idx < 4 * IN_CH; idx += 128)
        nm[idx] = node_mat[i0 * IN_CH + idx];
    __syncthreads();
    int o = tid;
    float accp[4] = {0.f, 0.f, 0.f, 0.f};
    float accr[4] = {0.f, 0.f, 0.f, 0.f};
    for (int c = 0; c < IN_CH; ++c) {
        float w  = node_weight[c * OUT_CH + o];
        float rt = root[c * OUT_CH + o];
#pragma unroll
        for (int i = 0; i < 4; ++i) {
            accp[i] += nm[i * IN_CH + c] * w;
            accr[i] += nm[i * IN_CH + c] * rt;
        }
    }
#pragma unroll
    for (int i = 0; i < 4; ++i) {
        P[(i0 + i) * OUT_CH + o] = accp[i];
        R[(i0 + i) * OUT_CH + o] = accr[i];
    }
}

// Kernel B (heavy): G[n,b] = sum_m adj[n,m] * relu( sum_e edge_adj[e,n,m] * L1[e,b] )
// One block (256 thr = 4 waves) per n. MFMA 16x16x32 bf16: A = L1^T tile (b x e),
// B = edge_adj (e x 16 m's), K=32 covers EDGE_CH exactly.
// A-frag layout: lane holds A[row=lane&15][k=quad*8+j]; B-frag: B[k=quad*8+j][col=lane&15];
// D: row=quad*4+r, col=lane&15.
__global__ void edge_g_kernel(const float* __restrict__ edge_adj,
                              const float* __restrict__ adj,
                              const float* __restrict__ L1,
                              float* __restrict__ G) {
    int n = blockIdx.x;
    int tid = threadIdx.x;
    int wave = tid >> 6;
    int lane = tid & 63;
    int quad = lane >> 4;
    int col  = lane & 15;

    // Preload constant A fragments: 8 b-tiles of L1^T [b=bt*16+col][e=quad*8+j]
    bf16x8 a_frag[8];
#pragma unroll
    for (int bt = 0; bt < 8; ++bt) {
        int b = bt * 16 + col;
#pragma unroll
        for (int j = 0; j < 8; ++j) {
            int e = quad * 8 + j;
            float v = (b < OUT_CH - 1) ? L1[e * (OUT_CH - 1) + b] : 0.0f;  // pad b=127
            a_frag[bt][j] = f2bf(v);
        }
    }

    float g_acc[8][4];
#pragma unroll
    for (int bt = 0; bt < 8; ++bt)
#pragma unroll
        for (int r = 0; r < 4; ++r) g_acc[bt][r] = 0.0f;

    const float* adj_row = adj + (size_t)n * NN;
    const float* ea_base = edge_adj + (size_t)n * NN;   // + e*NN*NN + m

    for (int m0 = wave * 16; m0 < NN; m0 += 64) {
        int m = m0 + col;
        float adjv = adj_row[m];

        bf16x8 b_frag;
#pragma unroll
        for (int j = 0; j < 8; ++j) {
            size_t e = (size_t)(quad * 8 + j);
            float v = ea_base[e * (size_t)(NN * NN) + m];
            b_frag[j] = f2bf(v);
        }

#pragma unroll
        for (int bt = 0; bt < 8; ++bt) {
            f32x4 d = __builtin_amdgcn_mfma_f32_16x16x32_bf16(
                a_frag[bt], b_frag, (f32x4){0.f, 0.f, 0.f, 0.f}, 0, 0, 0);
#pragma unroll
            for (int r = 0; r < 4; ++r)
                g_acc[bt][r] += fmaxf(d[r], 0.0f) * adjv;
        }
    }

    // reduce over the 16 column-lanes of each quad (sum over this lane's m subset)
#pragma unroll
    for (int bt = 0; bt < 8; ++bt)
#pragma unroll
        for (int r = 0; r < 4; ++r) {
            float v = g_acc[bt][r];
            v += __shfl_xor(v, 1);
            v += __shfl_xor(v, 2);
            v += __shfl_xor(v, 4);
            v += __shfl_xor(v, 8);
            g_acc[bt][r] = v;
        }

    // cross-wave reduction
    __shared__ float gred[4][OUT_CH];
    if (col == 0) {
#pragma unroll
        for (int bt = 0; bt < 8; ++bt)
#pragma unroll
            for (int r = 0; r < 4; ++r)
                gred[wave][bt * 16 + quad * 4 + r] = g_acc[bt][r];
    }
    __syncthreads();
    if (tid < OUT_CH)
        G[(size_t)n * OUT_CH + tid] =
            gred[0][tid] + gred[1][tid] + gred[2][tid] + gred[3][tid];
}

// Kernel C: out[n,o] = (adj @ P)[n,o] + (G[:, :127] @ L2)[n,o] + R[n,o] + bias[o]
// grid 256 blocks x 256 threads; block handles 4 n's; m-loop split across 2 halves.
__global__ void combine_kernel(const float* __restrict__ adj,
                               const float* __restrict__ P,
                               const float* __restrict__ G,
                               const float* __restrict__ L2,
                               const float* __restrict__ R,
                               const float* __restrict__ bias,
                               float* __restrict__ out) {
    __shared__ float adj_lds[4 * NN];     // 16 KB
    __shared__ float g_lds[4 * OUT_CH];   // 2 KB
    __shared__ float part[8 * OUT_CH];    // 4 KB
    int tid = threadIdx.x;
    int n0 = blockIdx.x * 4;
    int o = tid & 127;
    int half = tid >> 7;

    for (int idx = tid; idx < 4 * NN; idx += 256)
        adj_lds[idx] = adj[(size_t)n0 * NN + idx];
    for (int idx = tid; idx < 4 * OUT_CH; idx += 256)
        g_lds[idx] = G[(size_t)n0 * OUT_CH + idx];
    __syncthreads();

    float acc[4] = {0.f, 0.f, 0.f, 0.f};
    int mlo = half * 512;
    for (int m = mlo; m < mlo + 512; ++m) {
        float pv = P[m * OUT_CH + o];
#pragma unroll
        for (int i = 0; i < 4; ++i)
            acc[i] += adj_lds[i * NN + m] * pv;
    }
    // b-loop over 127 real edge channels, split across halves
    int b_lo = half * 64, b_hi = half ? 127 : 64;
    for (int b = b_lo; b < b_hi; ++b) {
        float l2v = L2[b * OUT_CH + o];
#pragma unroll
        for (int i = 0; i < 4; ++i)
            acc[i] += g_lds[i * OUT_CH + b] * l2v;
    }
#pragma unroll
    for (int i = 0; i < 4; ++i)
        part[(half * 4 + i) * OUT_CH + o] = acc[i];
    __syncthreads();
    if (tid < 128) {
        float bv = bias[o];
#pragma unroll
        for (int i = 0; i < 4; ++i)
            out[(size_t)(n0 + i) * OUT_CH + o] =
                part[i * OUT_CH + o] + part[(4 + i) * OUT_CH + o] +
                R[(size_t)(n0 + i) * OUT_CH + o] + bv;
    }
}

extern "C" void kernel_launch(void* const* d_in, const int* in_sizes, int n_in,
                              void* d_out, int out_size, void* d_ws, size_t ws_size,
                              hipStream_t stream) {
    const float* node_mat    = (const float*)d_in[0];
    const float* adj         = (const float*)d_in[1];
    const float* edge_adj    = (const float*)d_in[2];
    const float* node_weight = (const float*)d_in[3];
    const float* edge_lay_1  = (const float*)d_in[4];
    const float* edge_lay_2  = (const float*)d_in[5];
    const float* root        = (const float*)d_in[6];
    const float* bias        = (const float*)d_in[7];
    float* out = (float*)d_out;

    float* P = (float*)d_ws;                 // 1024*128
    float* R = P + NN * OUT_CH;              // 1024*128
    float* G = R + NN * OUT_CH;              // 1024*128

    node_gemm_kernel<<<NN / 4, 128, 0, stream>>>(node_mat, node_weight, root, P, R);
    edge_g_kernel<<<NN, 256, 0, stream>>>(edge_adj, adj, edge_lay_1, G);
    combine_kernel<<<NN / 4, 256, 0, stream>>>(adj, P, G, edge_lay_2, R, bias, out);
}

// Round 2
// 245.290 us; speedup vs baseline: 1.5540x; 1.5540x over previous
//
#include <hip/hip_runtime.h>
#include <hip/hip_bf16.h>

#define NN 1024
#define IN_CH 128
#define EDGE_CH 32
#define OUT_CH 128

typedef __attribute__((ext_vector_type(8))) short bf16x8;
typedef __attribute__((ext_vector_type(4))) float f32x4;

// round-to-nearest-even float -> bf16 (bit trick)
static __device__ __forceinline__ short f2bf(float f) {
    union { float f; unsigned u; } v; v.f = f;
    unsigned r = v.u + 0x7FFFu + ((v.u >> 16) & 1u);
    return (short)(r >> 16);
}

// ---------------------------------------------------------------------------
// Kernel A: P = node_mat @ node_weight (stored TRANSPOSED, bf16: PT[o][m]),
//           R = node_mat @ root (fp32).
// grid 512 x 256: block = 2 node-rows, thread (h = tid>>7) owns one row,
// o = tid & 127. node_weight/root columns are L1/L2-cached across blocks.
// ---------------------------------------------------------------------------
__global__ void node_gemm_kernel(const float* __restrict__ node_mat,
                                 const float* __restrict__ node_weight,
                                 const float* __restrict__ root,
                                 short* __restrict__ PT,
                                 float* __restrict__ R) {
    __shared__ float nm[2 * IN_CH];
    int tid = threadIdx.x;
    int n0 = blockIdx.x * 2;
    nm[tid] = node_mat[n0 * IN_CH + tid];
    __syncthreads();
    int o = tid & 127;
    int h = tid >> 7;
    const float* nr = &nm[h * IN_CH];
    float accp = 0.f, accr = 0.f;
#pragma unroll 8
    for (int c = 0; c < IN_CH; ++c) {
        float x = nr[c];
        accp += x * node_weight[c * OUT_CH + o];
        accr += x * root[c * OUT_CH + o];
    }
    R[(size_t)(n0 + h) * OUT_CH + o] = accr;
    PT[(size_t)o * NN + (n0 + h)] = f2bf(accp);  // transposed bf16 store
}

// ---------------------------------------------------------------------------
// Kernel B (heavy): per node n,
//   G[b]   = sum_m adj[n,m] * relu( sum_e edge_adj[e,n,m] * L1[e,b] )
//   out[n,o] = sum_{b<127} G[b]*L2[b,o] + R[n,o] + bias[o]
// One block (4 waves) per n. MFMA 16x16x32 bf16, K=32 = EDGE_CH exactly.
// A-frag: lane holds A[row=lane&15][k=quad*8+j]; B-frag: B[k=quad*8+j][col=lane&15];
// D: row=quad*4+r, col=lane&15.  (layouts verified by round-1 pass)
// m-loop unrolled x4: 36 independent global loads in flight per wave -> MLP.
// ---------------------------------------------------------------------------
__global__ void edge_out_kernel(const float* __restrict__ edge_adj,
                                const float* __restrict__ adj,
                                const float* __restrict__ L1,
                                const float* __restrict__ L2,
                                const float* __restrict__ R,
                                const float* __restrict__ bias,
                                float* __restrict__ out) {
    int n = blockIdx.x;
    int tid = threadIdx.x;
    int wave = tid >> 6;
    int lane = tid & 63;
    int quad = lane >> 4;
    int col  = lane & 15;

    // Preload constant A fragments: 8 b-tiles of L1^T [b=bt*16+col][e=quad*8+j]
    bf16x8 a_frag[8];
#pragma unroll
    for (int bt = 0; bt < 8; ++bt) {
        int b = bt * 16 + col;
#pragma unroll
        for (int j = 0; j < 8; ++j) {
            int e = quad * 8 + j;
            float v = (b < OUT_CH - 1) ? L1[e * (OUT_CH - 1) + b] : 0.0f;  // pad b=127
            a_frag[bt][j] = f2bf(v);
        }
    }

    float g_acc[8][4];
#pragma unroll
    for (int bt = 0; bt < 8; ++bt)
#pragma unroll
        for (int r = 0; r < 4; ++r) g_acc[bt][r] = 0.0f;

    const float* adj_row = adj + (size_t)n * NN;
    const float* ea_base = edge_adj + (size_t)n * NN;   // + e*NN*NN + m

    // wave w owns m in [w*256, w*256+256), processed as 4 chunks of 64 m,
    // each chunk = 4 sub-tiles of 16 m. All 36 loads of a chunk are issued
    // before the MFMA block (independent).
    for (int c = 0; c < 4; ++c) {
        int base = wave * 256 + c * 64;
        float adjv[4];
        bf16x8 bf[4];
#pragma unroll
        for (int s = 0; s < 4; ++s) {
            int m = base + s * 16 + col;
            adjv[s] = adj_row[m];
#pragma unroll
            for (int j = 0; j < 8; ++j) {
                size_t e = (size_t)(quad * 8 + j);
                bf[s][j] = f2bf(ea_base[e * (size_t)(NN * NN) + m]);
            }
        }
#pragma unroll
        for (int s = 0; s < 4; ++s) {
#pragma unroll
            for (int bt = 0; bt < 8; ++bt) {
                f32x4 d = __builtin_amdgcn_mfma_f32_16x16x32_bf16(
                    a_frag[bt], bf[s], (f32x4){0.f, 0.f, 0.f, 0.f}, 0, 0, 0);
#pragma unroll
                for (int r = 0; r < 4; ++r)
                    g_acc[bt][r] += fmaxf(d[r], 0.0f) * adjv[s];
            }
        }
    }

    // reduce over the 16 column-lanes of each quad (sum over this lane's m's)
#pragma unroll
    for (int bt = 0; bt < 8; ++bt)
#pragma unroll
        for (int r = 0; r < 4; ++r) {
            float v = g_acc[bt][r];
            v += __shfl_xor(v, 1);
            v += __shfl_xor(v, 2);
            v += __shfl_xor(v, 4);
            v += __shfl_xor(v, 8);
            g_acc[bt][r] = v;
        }

    __shared__ float gred[4][OUT_CH];
    __shared__ float gs[OUT_CH];
    __shared__ float part[2][OUT_CH];
    if (col == 0) {
#pragma unroll
        for (int bt = 0; bt < 8; ++bt)
#pragma unroll
            for (int r = 0; r < 4; ++r)
                gred[wave][bt * 16 + quad * 4 + r] = g_acc[bt][r];
    }
    __syncthreads();
    if (tid < OUT_CH)
        gs[tid] = gred[0][tid] + gred[1][tid] + gred[2][tid] + gred[3][tid];
    __syncthreads();

    // epilogue: out[n,o] = sum_{b<127} gs[b]*L2[b,o] + R[n,o] + bias[o]
    int o = tid & 127;
    int hf = tid >> 7;
    float acc = 0.f;
    int blo = hf * 64, bhi = hf ? 127 : 64;
#pragma unroll 8
    for (int b = blo; b < bhi; ++b)
        acc += gs[b] * L2[b * OUT_CH + o];   // gs[b] is an LDS broadcast (free)
    part[hf][o] = acc;
    __syncthreads();
    if (tid < 128)
        out[(size_t)n * OUT_CH + tid] =
            part[0][tid] + part[1][tid] + R[(size_t)n * OUT_CH + tid] + bias[tid];
}

// ---------------------------------------------------------------------------
// Kernel C: out += adj @ P  via MFMA bf16, K-split, fp32 atomicAdd.
// grid 512 = 32 n-tiles (32 rows) x 16 K-chunks (64 k each). Block 4 waves:
// wave (nh = w&1, oh = w>>1) does 16 n x 64 o x K=64 (2 K-steps, 4 o-tiles).
// A = adj rows (fp32 -> bf16, 32-B loads); B = PT[o][k] bf16 (16-B loads,
// exactly the B-frag layout). out was fully written by edge_out_kernel first.
// ---------------------------------------------------------------------------
__global__ void adjp_kernel(const float* __restrict__ adj,
                            const short* __restrict__ PT,
                            float* __restrict__ out) {
    int blk = blockIdx.x;
    int nb = blk & 31;
    int kc = blk >> 5;          // 0..15
    int tid = threadIdx.x;
    int wave = tid >> 6;
    int lane = tid & 63;
    int quad = lane >> 4;
    int col  = lane & 15;
    int nh = wave & 1;
    int oh = wave >> 1;
    int n0 = nb * 32 + nh * 16;
    int k0 = kc * 64;

    f32x4 acc[4];
#pragma unroll
    for (int ot = 0; ot < 4; ++ot) acc[ot] = (f32x4){0.f, 0.f, 0.f, 0.f};

#pragma unroll
    for (int ks = 0; ks < 2; ++ks) {
        int k = k0 + ks * 32 + quad * 8;
        const float* ap = adj + (size_t)(n0 + col) * NN + k;
        bf16x8 a;
#pragma unroll
        for (int j = 0; j < 8; ++j) a[j] = f2bf(ap[j]);
#pragma unroll
        for (int ot = 0; ot < 4; ++ot) {
            int o = oh * 64 + ot * 16 + col;
            bf16x8 b = *(const bf16x8*)(PT + (size_t)o * NN + k);
            acc[ot] = __builtin_amdgcn_mfma_f32_16x16x32_bf16(a, b, acc[ot], 0, 0, 0);
        }
    }

#pragma unroll
    for (int ot = 0; ot < 4; ++ot)
#pragma unroll
        for (int r = 0; r < 4; ++r)
            atomicAdd(&out[(size_t)(n0 + quad * 4 + r) * OUT_CH + oh * 64 + ot * 16 + col],
                      acc[ot][r]);
}

extern "C" void kernel_launch(void* const* d_in, const int* in_sizes, int n_in,
                              void* d_out, int out_size, void* d_ws, size_t ws_size,
                              hipStream_t stream) {
    const float* node_mat    = (const float*)d_in[0];
    const float* adj         = (const float*)d_in[1];
    const float* edge_adj    = (const float*)d_in[2];
    const float* node_weight = (const float*)d_in[3];
    const float* edge_lay_1  = (const float*)d_in[4];
    const float* edge_lay_2  = (const float*)d_in[5];
    const float* root        = (const float*)d_in[6];
    const float* bias        = (const float*)d_in[7];
    float* out = (float*)d_out;

    short* PT = (short*)d_ws;                       // 128*1024 bf16 = 256 KB
    float* R  = (float*)((char*)d_ws + OUT_CH * NN * sizeof(short));  // 512 KB

    node_gemm_kernel<<<NN / 2, 256, 0, stream>>>(node_mat, node_weight, root, PT, R);
    edge_out_kernel<<<NN, 256, 0, stream>>>(edge_adj, adj, edge_lay_1, edge_lay_2,
                                            R, bias, out);
    adjp_kernel<<<512, 256, 0, stream>>>(adj, PT, out);
}